// Round 3
// baseline (838.150 us; speedup 1.0000x reference)
//
#include <hip/hip_runtime.h>
#include <hip/hip_bf16.h>
#include <math.h>

// ---------------------------------------------------------------------------
// ToyMoE: top-1 routed 2-expert MLP. H=2048, tokens = 8192.
//   R2: 770us. GEMMs 2x243us @565TF, conflicts 1.7e7.
//   R3: 680us. BK=64: GEMMs 2x228us, conflicts 5.1e7.
//   R4: 621us. XOR-swizzled LDS (conflicts 0), GEMMs 2x190us @723TF.
//   R5: 852us REGRESSION. 256^2 8-phase, plain-C++ LDS reads. MfmaUtil 17%.
//   R6: 791us. asm ds_read + manual waits: 317us/GEMM, MfmaUtil 18% --
//       UNCHANGED vs R5 => the drain is not attached to the reads.
//   R7: theory: LLVM attaches a conservative `s_waitcnt vmcnt(0)` to the
//       *builtin* s_barrier whenever LDS-DMA (global_load_lds) is
//       outstanding (DMA results become cross-wave-visible at a barrier).
//       That drains the prefetch queue 8x per K-tile in R5 AND R6.
//       Fix: raw-asm `s_barrier` (opaque to the waitcnt pass); all sync in
//       the K-loop is now explicitly programmer-owned.
// ---------------------------------------------------------------------------

#define HDIM   2048
#define TOKENS 8192
#define FDIM   4096   // 2*H

typedef __bf16 bf16x8 __attribute__((ext_vector_type(8)));
typedef __bf16 bf16x4 __attribute__((ext_vector_type(4)));
typedef float  f32x4  __attribute__((ext_vector_type(4)));

// workspace layout (bytes)
#define CNT_OFF  0           // n0 (int), n1 (int)
#define PERM_OFF 256         // int[8192]
#define XG_OFF   65536       // bf16 [8192][2048]   = 33554432 B
#define WA_OFF   33619968    // bf16 [2][4096][2048] = 33554432 B
#define WB_OFF   67174400    // bf16 [2][2048][4096] = 33554432 B
#define HB_OFF   100728832   // bf16 [8192][4096]    = 67108864 B

typedef __attribute__((address_space(1))) const unsigned int as1_u32;
typedef __attribute__((address_space(3))) unsigned int       as3_u32;
typedef __attribute__((address_space(3))) __bf16             lds_bf16_t;

__device__ __forceinline__ void gl2lds16(const void* g, void* l) {
    __builtin_amdgcn_global_load_lds((as1_u32*)g, (as3_u32*)l, 16, 0, 0);
}

// Raw barrier: opaque to SIInsertWaitcnts, so no compiler-attached
// `s_waitcnt vmcnt(0)` drain of the LDS-DMA queue. Memory clobber keeps
// program order vs the gl2lds intrinsics and the explicit wait asm.
#define BAR() asm volatile("s_barrier" ::: "memory")

// Opaque LDS read: all ordering owned by explicit s_waitcnt (rule 18).
__device__ __forceinline__ bf16x8 ldsr128(unsigned addr) {
    bf16x8 r;
    asm volatile("ds_read_b128 %0, %1" : "=v"(r) : "v"(addr));
    return r;
}

// ------- fused gate(fp64 argmax) + routed gather + bf16 cast ---------------
// block = 256 threads = 4 waves; wave w gates+copies token blockIdx.x*4+w.
__global__ void moe_gate_gather(const float* __restrict__ x, const float* __restrict__ Wg,
                                int* __restrict__ n0, int* __restrict__ n1,
                                int* __restrict__ perm, __bf16* __restrict__ Xg) {
    __shared__ int sel[4];
    __shared__ int pos[4];
    const int tid  = threadIdx.x;
    const int wid  = tid >> 6;
    const int lane = tid & 63;
    const int token = blockIdx.x * 4 + wid;
    const float* xr = x + (size_t)token * HDIM;

    float4 xv[8];
    double s0 = 0.0, s1 = 0.0;
#pragma unroll
    for (int j = 0; j < 8; j++) {
        const int idx = j * 256 + lane * 4;
        xv[j] = *reinterpret_cast<const float4*>(xr + idx);
        float4 g0 = *reinterpret_cast<const float4*>(Wg + idx);
        float4 g1 = *reinterpret_cast<const float4*>(Wg + HDIM + idx);
        s0 += (double)xv[j].x * g0.x + (double)xv[j].y * g0.y
            + (double)xv[j].z * g0.z + (double)xv[j].w * g0.w;
        s1 += (double)xv[j].x * g1.x + (double)xv[j].y * g1.y
            + (double)xv[j].z * g1.z + (double)xv[j].w * g1.w;
    }
#pragma unroll
    for (int off = 32; off > 0; off >>= 1) {
        s0 += __shfl_down(s0, off);
        s1 += __shfl_down(s1, off);
    }
    if (lane == 0) sel[wid] = (s1 > s0) ? 1 : 0;   // softmax monotone; ties -> e0
    __syncthreads();
    if (tid == 0) {
        int c0 = (sel[0] == 0) + (sel[1] == 0) + (sel[2] == 0) + (sel[3] == 0);
        int p0 = c0 ? atomicAdd(n0, c0) : 0;
        int p1 = (c0 < 4) ? atomicAdd(n1, 4 - c0) : 0;
#pragma unroll
        for (int w = 0; w < 4; w++) {
            if (sel[w] == 0) pos[w] = p0++;
            else             pos[w] = TOKENS - 1 - (p1++);
        }
    }
    __syncthreads();
    const int dst = pos[wid];
    if (lane == 0) perm[dst] = token;
    __bf16* dr = Xg + (size_t)dst * HDIM;
#pragma unroll
    for (int j = 0; j < 8; j++) {
        const int idx = j * 256 + lane * 4;
        bf16x4 v;
        v[0] = (__bf16)xv[j].x; v[1] = (__bf16)xv[j].y;
        v[2] = (__bf16)xv[j].z; v[3] = (__bf16)xv[j].w;
        *reinterpret_cast<bf16x4*>(dr + idx) = v;
    }
}

// ---------------- cast the 4 expert weight matrices to bf16 -----------------
__global__ void moe_cast_w(const float* __restrict__ W0a, const float* __restrict__ W1a,
                           const float* __restrict__ W0b, const float* __restrict__ W1b,
                           __bf16* __restrict__ Wa, __bf16* __restrict__ Wb) {
    const int slice = blockIdx.y;
    const float* src;
    __bf16* dst;
    const size_t MS = (size_t)FDIM * HDIM;
    if      (slice == 0) { src = W0a; dst = Wa; }
    else if (slice == 1) { src = W1a; dst = Wa + MS; }
    else if (slice == 2) { src = W0b; dst = Wb; }
    else                 { src = W1b; dst = Wb + MS; }
    const size_t idx = ((size_t)blockIdx.x * 256 + threadIdx.x) * 8;
    float4 a = *reinterpret_cast<const float4*>(src + idx);
    float4 b = *reinterpret_cast<const float4*>(src + idx + 4);
    bf16x8 v;
    v[0] = (__bf16)a.x; v[1] = (__bf16)a.y; v[2] = (__bf16)a.z; v[3] = (__bf16)a.w;
    v[4] = (__bf16)b.x; v[5] = (__bf16)b.y; v[6] = (__bf16)b.z; v[7] = (__bf16)b.w;
    *reinterpret_cast<bf16x8*>(dst + idx) = v;
}

// ---------------- MFMA GEMM, 256x256 tile, BK=64, 8-phase schedule ---------
// A:[8192][KDIM] bf16, Bw:[2][NDIM][KDIM] bf16 (K-contiguous, B^T GEMM).
// 8 waves (2M x 4N), per-wave 128x64 output, acc[8][4] f32x4.
// LDS: 2 buffers x (A 256x64 + B 256x64) bf16 = 128 KiB, XOR chunk-swizzle.
// Per K-tile 4 phases; each: {asm ds_read subtile; stage 1 half-tile;
//   [lgkmcnt(8) if 12 reads]; BAR; lgkmcnt(0); sched_barrier(0);
//   setprio(1); 16 MFMA; setprio(0); BAR}. vmcnt(6) once per tile @P4.
// Region safety: reads of {A-rh0, B, A-rh1} retire at {P1,P2,P3}; overwrites
//   (tile k+2) issued at {P2,P3/P4,next-P1}, each behind the retiring barrier.
// vmcnt accounting (hand-traced): at tile-k start, 6 outstanding =
//   T+1.{A0,B-lo,B-hi}; P1 adds T+1.A1; P4's vmcnt(6) retires exactly T+1.
// DOWN=true: split-K2 (z = e*2+kb), fp32 atomicAdd into pre-zeroed Out.
template <int KDIM, int NDIM, bool DOWN>
__global__ __launch_bounds__(512, 2) void moe_gemm8(
        const __bf16* __restrict__ A, const __bf16* __restrict__ Bw,
        const float* __restrict__ bias0, const float* __restrict__ bias1,
        __bf16* __restrict__ Hb, float* __restrict__ Out,
        const int* __restrict__ n0_ptr, const int* __restrict__ perm) {
    constexpr int KSPAN = DOWN ? KDIM / 2 : KDIM;   // K range per block
    constexpr int NT    = KSPAN / 64;               // 32 for both GEMMs

    const int z  = blockIdx.z;
    const int e  = DOWN ? (z >> 1) : z;
    const int kb = DOWN ? (z & 1)  : 0;
    const int n0 = *n0_ptr;
    const int row_lo = e ? n0 : 0;
    const int row_hi = e ? TOKENS : n0;
    const int bm = blockIdx.y * 256;
    if (bm >= row_hi || bm + 256 <= row_lo) return;
    const int bn = blockIdx.x * 256;

    __shared__ __bf16 As[2][256 * 64];   // 2 x 32 KiB
    __shared__ __bf16 Bs[2][256 * 64];   // 2 x 32 KiB

    const int tid  = threadIdx.x;
    const int wid  = tid >> 6;           // 0..7
    const int lane = tid & 63;
    const int wr   = wid >> 2;           // 0..1 (M)
    const int wc   = wid & 3;            // 0..3 (N)

    const __bf16* Be   = Bw + (size_t)e * NDIM * KDIM;
    const float*  bias = e ? bias1 : bias0;

    // ---- staging geometry: one gl2lds = 8 rows x 128 B (64 lanes x 16 B).
    // Lane l -> LDS slot (row +(l>>3), chunk l&7); source chunk pre-swizzled.
    const int skol = ((lane & 7) ^ (lane >> 3)) * 8;
    const __bf16* gA = A  + (size_t)(bm + (wid >> 2) * 128 + (wid & 3) * 16 + (lane >> 3)) * KDIM
                          + (size_t)kb * KSPAN + skol;
    const __bf16* gB = Be + (size_t)(bn + wid * 16 + (lane >> 3)) * KDIM
                          + (size_t)kb * KSPAN + skol;
    const int al = ((wid >> 2) * 128 + (wid & 3) * 16) * 64;  // LDS elem offset (A)
    const int bl = (wid * 16) * 64;                           // LDS elem offset (B)

    auto stageA = [&](int buf, int rh, int kt) {
        gl2lds16(gA + (size_t)(rh * 64    ) * KDIM + kt, &As[buf][al + (rh * 64    ) * 64]);
        gl2lds16(gA + (size_t)(rh * 64 + 8) * KDIM + kt, &As[buf][al + (rh * 64 + 8) * 64]);
    };
    auto stageB = [&](int buf, int hb, int kt) {
        gl2lds16(gB + (size_t)(hb * 128    ) * KDIM + kt, &Bs[buf][bl + (hb * 128    ) * 64]);
        gl2lds16(gB + (size_t)(hb * 128 + 8) * KDIM + kt, &Bs[buf][bl + (hb * 128 + 8) * 64]);
    };

    // ---- fragment-read geometry (zero-conflict, measured R4) ----
    const int rm  = lane & 15;
    const int g   = lane >> 4;           // 0..3
    const int rsw = rm & 7;              // read-side swizzle key
    const int ra  = (wr * 128 + rm) * 64;
    const int rb  = (wc * 64  + rm) * 64;
    const int c0  = ((0 + g) ^ rsw) * 8; // kk=0 chunk (elem offset)
    const int c1  = ((4 + g) ^ rsw) * 8; // kk=1 chunk

    // 32-bit LDS byte addresses for the asm reads.
    const unsigned asBase = (unsigned)(size_t)(lds_bf16_t*)&As[0][0];
    const unsigned bsBase = (unsigned)(size_t)(lds_bf16_t*)&Bs[0][0];
    const unsigned aAdr0 = asBase + (unsigned)(ra + c0) * 2u;
    const unsigned aAdr1 = asBase + (unsigned)(ra + c1) * 2u;
    const unsigned bAdr0 = bsBase + (unsigned)(rb + c0) * 2u;
    const unsigned bAdr1 = bsBase + (unsigned)(rb + c1) * 2u;

    f32x4  acc[8][4] = {};
    bf16x8 aF[2][4], bF[2][4];

    auto mmaQ = [&](int io, int jo) {   // 16 MFMA: one C-quadrant x K=64
#pragma unroll
        for (int i2 = 0; i2 < 4; i2++)
#pragma unroll
            for (int j = 0; j < 2; j++)
#pragma unroll
                for (int kk = 0; kk < 2; kk++)
                    acc[io + i2][jo + j] = __builtin_amdgcn_mfma_f32_16x16x32_bf16(
                        aF[kk][i2], bF[kk][jo + j], acc[io + i2][jo + j], 0, 0, 0);
    };

    // ---- prologue: T0 {A0,A1,B0,B1} + T1 {A0,B0,B1}; vmcnt(6) -> T0 landed
    stageA(0, 0, 0);  stageA(0, 1, 0);  stageB(0, 0, 0);  stageB(0, 1, 0);
    stageA(1, 0, 64); stageB(1, 0, 64); stageB(1, 1, 64);
    asm volatile("s_waitcnt vmcnt(6)" ::: "memory");
    __builtin_amdgcn_sched_barrier(0);
    BAR();

    for (int k = 0; k < NT; ++k) {
        const int      cur = k & 1;
        const unsigned bo  = cur ? 32768u : 0u;
        const int      kt1 = (k + 1) * 64;
        const int      kt2 = (k + 2) * 64;
        const bool     s1  = (k + 1 < NT);
        const bool     s2  = (k + 2 < NT);

        // ---- P1: read A(rh0)+B(j0,1) [12]; stage T+1.A-rh1 -> buf^1
#pragma unroll
        for (int kk = 0; kk < 2; kk++) {
            const unsigned ab = (kk ? aAdr1 : aAdr0) + bo;
            const unsigned bb = (kk ? bAdr1 : bAdr0) + bo;
#pragma unroll
            for (int i2 = 0; i2 < 4; i2++) aF[kk][i2] = ldsr128(ab + (unsigned)i2 * 2048u);
#pragma unroll
            for (int j = 0; j < 2; j++)    bF[kk][j]  = ldsr128(bb + (unsigned)j * 2048u);
        }
        if (s1) stageA(cur ^ 1, 1, kt1);
        asm volatile("s_waitcnt lgkmcnt(8)" ::: "memory");
        BAR();
        asm volatile("s_waitcnt lgkmcnt(0)" ::: "memory");
        __builtin_amdgcn_sched_barrier(0);
        __builtin_amdgcn_s_setprio(1);
        mmaQ(0, 0);
        __builtin_amdgcn_s_setprio(0);
        BAR();

        // ---- P2: read B(j2,3) [4]; stage T+2.A-rh0 -> buf cur
#pragma unroll
        for (int kk = 0; kk < 2; kk++) {
            const unsigned bb = (kk ? bAdr1 : bAdr0) + bo;
#pragma unroll
            for (int j = 0; j < 2; j++) bF[kk][2 + j] = ldsr128(bb + (unsigned)(2 + j) * 2048u);
        }
        if (s2) stageA(cur, 0, kt2);
        BAR();
        asm volatile("s_waitcnt lgkmcnt(0)" ::: "memory");
        __builtin_amdgcn_sched_barrier(0);
        __builtin_amdgcn_s_setprio(1);
        mmaQ(0, 2);
        __builtin_amdgcn_s_setprio(0);
        BAR();

        // ---- P3: read A(rh1) [8]; stage T+2.B-lo -> buf cur
#pragma unroll
        for (int kk = 0; kk < 2; kk++) {
            const unsigned ab = (kk ? aAdr1 : aAdr0) + bo + 8192u;
#pragma unroll
            for (int i2 = 0; i2 < 4; i2++) aF[kk][i2] = ldsr128(ab + (unsigned)i2 * 2048u);
        }
        if (s2) stageB(cur, 0, kt2);
        BAR();
        asm volatile("s_waitcnt lgkmcnt(0)" ::: "memory");
        __builtin_amdgcn_sched_barrier(0);
        __builtin_amdgcn_s_setprio(1);
        mmaQ(4, 0);
        __builtin_amdgcn_s_setprio(0);
        BAR();

        // ---- P4: no reads; stage T+2.B-hi; vmcnt(6) -> T+1 fully landed
        if (s2) stageB(cur, 1, kt2);
        BAR();
        __builtin_amdgcn_s_setprio(1);
        mmaQ(4, 2);
        __builtin_amdgcn_s_setprio(0);
        if (s2) { asm volatile("s_waitcnt vmcnt(6)" ::: "memory"); }
        else    { asm volatile("s_waitcnt vmcnt(0)" ::: "memory"); }
        __builtin_amdgcn_sched_barrier(0);
        BAR();
    }

    // ---- epilogue. C/D layout: col = lane&15, row = (lane>>4)*4 + reg [m89/m91]
    const int q4 = g * 4;
#pragma unroll
    for (int j = 0; j < 4; j++) {
        const int col = bn + wc * 64 + j * 16 + rm;
        const float bv = DOWN ? ((kb == 0) ? bias[col] : 0.0f) : bias[col];
#pragma unroll
        for (int i = 0; i < 8; i++) {
            const int rbase = bm + wr * 128 + i * 16 + q4;
#pragma unroll
            for (int r = 0; r < 4; r++) {
                const int row = rbase + r;
                if (row >= row_lo && row < row_hi) {
                    float v = acc[i][j][r] + bv;
                    if (!DOWN) {
                        if (e == 0) v = 0.5f * v * (1.0f + erff(v * 0.70710678118654752f));
                        else        v = v > 0.0f ? v : 0.0f;
                        Hb[(size_t)row * NDIM + col] = (__bf16)v;
                    } else {
                        atomicAdd(Out + (size_t)perm[row] * HDIM + col, v);
                    }
                }
            }
        }
    }
}

extern "C" void kernel_launch(void* const* d_in, const int* in_sizes, int n_in,
                              void* d_out, int out_size, void* d_ws, size_t ws_size,
                              hipStream_t stream) {
    const float* x   = (const float*)d_in[0];
    const float* Wg  = (const float*)d_in[1];
    const float* W0a = (const float*)d_in[2];
    const float* b0a = (const float*)d_in[3];
    const float* W0b = (const float*)d_in[4];
    const float* b0b = (const float*)d_in[5];
    const float* W1a = (const float*)d_in[6];
    const float* b1a = (const float*)d_in[7];
    const float* W1b = (const float*)d_in[8];
    const float* b1b = (const float*)d_in[9];
    float* out = (float*)d_out;

    char* w = (char*)d_ws;
    int* n0   = (int*)(w + CNT_OFF);
    int* n1   = n0 + 1;
    int* perm = (int*)(w + PERM_OFF);
    __bf16* Xg = (__bf16*)(w + XG_OFF);
    __bf16* Wa = (__bf16*)(w + WA_OFF);
    __bf16* Wb = (__bf16*)(w + WB_OFF);
    __bf16* Hb = (__bf16*)(w + HB_OFF);

    (void)hipMemsetAsync(w, 0, 256, stream);
    (void)hipMemsetAsync(out, 0, (size_t)TOKENS * HDIM * sizeof(float), stream);
    moe_gate_gather<<<TOKENS / 4, 256, 0, stream>>>(x, Wg, n0, n1, perm, Xg);
    moe_cast_w<<<dim3(4096, 4), 256, 0, stream>>>(W0a, W1a, W0b, W1b, Wa, Wb);
    moe_gemm8<HDIM, FDIM, false><<<dim3(FDIM / 256, TOKENS / 256, 2), 512, 0, stream>>>(
        Xg, Wa, b0a, b1a, Hb, nullptr, n0, perm);
    moe_gemm8<FDIM, HDIM, true><<<dim3(HDIM / 256, TOKENS / 256, 4), 512, 0, stream>>>(
        Hb, Wb, b0b, b1b, nullptr, out, n0, perm);
}

// Round 4
// 624.900 us; speedup vs baseline: 1.3413x; 1.3413x over previous
//
#include <hip/hip_runtime.h>
#include <hip/hip_bf16.h>
#include <math.h>

// ---------------------------------------------------------------------------
// ToyMoE: top-1 routed 2-expert MLP. H=2048, tokens = 8192.
//   R2: 770us. GEMMs 2x243us @565TF, conflicts 1.7e7.
//   R3: 680us. BK=64: GEMMs 2x228us, conflicts 5.1e7.
//   R4: 621us. XOR-swizzled LDS (conflicts 0), GEMMs 2x190us @723TF,
//       MfmaUtil 32% -> at the m97 2-barrier structural ceiling.
//   R5-R7: 256^2 8-phase port: 317-340us/GEMM, MfmaUtil 17-18% across all
//       three wait-ownership variants (compiler/manual/raw-asm) -> the
//       collapse is structural in my reconstruction, not wait insertion.
//       ABANDONED per pre-committed criterion; reverted to R4 base.
//   R8: R4 + MFMA shape 16x16x32 -> 32x32x16 (one variable). Pipe ceiling
//       2382 vs 2075 TF; halves MFMA issue count per FLOP; same staging,
//       same zero-conflict swizzle reads (8 consecutive lanes cover all 32
//       banks once). C/D layout m74/m101; A/B: row=lane&31, k=(lane>>5)*8+e.
// ---------------------------------------------------------------------------

#define HDIM   2048
#define TOKENS 8192
#define FDIM   4096   // 2*H

typedef __bf16 bf16x8 __attribute__((ext_vector_type(8)));
typedef __bf16 bf16x4 __attribute__((ext_vector_type(4)));
typedef float  f32x16 __attribute__((ext_vector_type(16)));

// workspace layout (bytes)
#define CNT_OFF  0           // n0 (int), n1 (int)
#define PERM_OFF 256         // int[8192]
#define XG_OFF   65536       // bf16 [8192][2048]   = 33554432 B
#define WA_OFF   33619968    // bf16 [2][4096][2048] = 33554432 B
#define WB_OFF   67174400    // bf16 [2][2048][4096] = 33554432 B
#define HB_OFF   100728832   // bf16 [8192][4096]    = 67108864 B

typedef __attribute__((address_space(1))) const unsigned int as1_u32;
typedef __attribute__((address_space(3))) unsigned int       as3_u32;

__device__ __forceinline__ void gl2lds16(const void* g, void* l) {
    __builtin_amdgcn_global_load_lds((as1_u32*)g, (as3_u32*)l, 16, 0, 0);
}

// ------- fused gate(fp64 argmax) + routed gather + bf16 cast ---------------
// block = 256 threads = 4 waves; wave w gates+copies token blockIdx.x*4+w.
__global__ void moe_gate_gather(const float* __restrict__ x, const float* __restrict__ Wg,
                                int* __restrict__ n0, int* __restrict__ n1,
                                int* __restrict__ perm, __bf16* __restrict__ Xg) {
    __shared__ int sel[4];
    __shared__ int pos[4];
    const int tid  = threadIdx.x;
    const int wid  = tid >> 6;
    const int lane = tid & 63;
    const int token = blockIdx.x * 4 + wid;
    const float* xr = x + (size_t)token * HDIM;

    float4 xv[8];
    double s0 = 0.0, s1 = 0.0;
#pragma unroll
    for (int j = 0; j < 8; j++) {
        const int idx = j * 256 + lane * 4;
        xv[j] = *reinterpret_cast<const float4*>(xr + idx);
        float4 g0 = *reinterpret_cast<const float4*>(Wg + idx);
        float4 g1 = *reinterpret_cast<const float4*>(Wg + HDIM + idx);
        s0 += (double)xv[j].x * g0.x + (double)xv[j].y * g0.y
            + (double)xv[j].z * g0.z + (double)xv[j].w * g0.w;
        s1 += (double)xv[j].x * g1.x + (double)xv[j].y * g1.y
            + (double)xv[j].z * g1.z + (double)xv[j].w * g1.w;
    }
#pragma unroll
    for (int off = 32; off > 0; off >>= 1) {
        s0 += __shfl_down(s0, off);
        s1 += __shfl_down(s1, off);
    }
    if (lane == 0) sel[wid] = (s1 > s0) ? 1 : 0;   // softmax monotone; ties -> e0
    __syncthreads();
    if (tid == 0) {
        int c0 = (sel[0] == 0) + (sel[1] == 0) + (sel[2] == 0) + (sel[3] == 0);
        int p0 = c0 ? atomicAdd(n0, c0) : 0;
        int p1 = (c0 < 4) ? atomicAdd(n1, 4 - c0) : 0;
#pragma unroll
        for (int w = 0; w < 4; w++) {
            if (sel[w] == 0) pos[w] = p0++;
            else             pos[w] = TOKENS - 1 - (p1++);
        }
    }
    __syncthreads();
    const int dst = pos[wid];
    if (lane == 0) perm[dst] = token;
    __bf16* dr = Xg + (size_t)dst * HDIM;
#pragma unroll
    for (int j = 0; j < 8; j++) {
        const int idx = j * 256 + lane * 4;
        bf16x4 v;
        v[0] = (__bf16)xv[j].x; v[1] = (__bf16)xv[j].y;
        v[2] = (__bf16)xv[j].z; v[3] = (__bf16)xv[j].w;
        *reinterpret_cast<bf16x4*>(dr + idx) = v;
    }
}

// ---------------- cast the 4 expert weight matrices to bf16 -----------------
__global__ void moe_cast_w(const float* __restrict__ W0a, const float* __restrict__ W1a,
                           const float* __restrict__ W0b, const float* __restrict__ W1b,
                           __bf16* __restrict__ Wa, __bf16* __restrict__ Wb) {
    const int slice = blockIdx.y;
    const float* src;
    __bf16* dst;
    const size_t MS = (size_t)FDIM * HDIM;
    if      (slice == 0) { src = W0a; dst = Wa; }
    else if (slice == 1) { src = W1a; dst = Wa + MS; }
    else if (slice == 2) { src = W0b; dst = Wb; }
    else                 { src = W1b; dst = Wb + MS; }
    const size_t idx = ((size_t)blockIdx.x * 256 + threadIdx.x) * 8;
    float4 a = *reinterpret_cast<const float4*>(src + idx);
    float4 b = *reinterpret_cast<const float4*>(src + idx + 4);
    bf16x8 v;
    v[0] = (__bf16)a.x; v[1] = (__bf16)a.y; v[2] = (__bf16)a.z; v[3] = (__bf16)a.w;
    v[4] = (__bf16)b.x; v[5] = (__bf16)b.y; v[6] = (__bf16)b.z; v[7] = (__bf16)b.w;
    *reinterpret_cast<bf16x8*>(dst + idx) = v;
}

// ---------------- MFMA GEMM, 128x128 tile, BK=64, 32x32x16 MFMA ------------
// A:[8192][KDIM] bf16, Bw:[2][NDIM][KDIM] bf16 (K-contiguous, B^T GEMM)
// 4 waves (2x2), per-wave 64x64 output as 2x2 of 32x32; acc f32x16 each.
// LDS layout (R4, zero-conflict): slot (row r, 16B-chunk c') holds global
// (r, c' ^ (r&7)); staged via per-lane pre-swizzled global source.
// A/B operand (lane l): row/col = l&31, k = (l>>5)*8 + e  (e in [0,8)).
// C/D (m74/m101): col = lane&31, row = (reg&3) + 8*(reg>>2) + 4*(lane>>5).
// DOWN=false: out = act(A*B^T + bias) -> Hb bf16; DOWN=true: fp32 scatter.
template <int KDIM, int NDIM, bool DOWN>
__global__ void moe_gemm(const __bf16* __restrict__ A, const __bf16* __restrict__ Bw,
                         const float* __restrict__ bias0, const float* __restrict__ bias1,
                         __bf16* __restrict__ Hb, float* __restrict__ Out,
                         const int* __restrict__ n0_ptr, const int* __restrict__ perm) {
    const int e  = blockIdx.z;
    const int n0 = *n0_ptr;
    const int row_lo = e ? n0 : 0;
    const int row_hi = e ? TOKENS : n0;
    const int bm = blockIdx.y * 128;
    if (bm >= row_hi || bm + 128 <= row_lo) return;
    const int bn = blockIdx.x * 128;

    __shared__ __bf16 As[128 * 64];   // 16 KB
    __shared__ __bf16 Bs[128 * 64];   // 16 KB

    const int tid  = threadIdx.x;
    const int wid  = tid >> 6;
    const int lane = tid & 63;

    const __bf16* Be   = Bw + (size_t)e * NDIM * KDIM;
    const float*  bias = e ? bias1 : bias0;

    // staging (BK=64): one gl2lds16 covers 8 rows x 128B. Lane l -> LDS slot
    // (row l>>3, chunk l&7); source chunk is XOR-swizzled: (l&7)^(l>>3).
    // Wave w stages rows [w*32, w*32+32) in 4 chunks of 8 rows.
    const int srow = wid * 32 + (lane >> 3);
    const int skol = (((lane & 7) ^ (lane >> 3)) * 8);   // swizzled source col
    const __bf16* gA = A  + (size_t)(bm + srow) * KDIM + skol;
    const __bf16* gB = Be + (size_t)(bn + srow) * KDIM + skol;
    __bf16* lA = &As[(wid * 32) * 64];
    __bf16* lB = &Bs[(wid * 32) * 64];

    const int wrow = (wid >> 1) * 64;
    const int wcol = (wid & 1) * 64;
    const int l31 = lane & 31;
    const int hi  = lane >> 5;       // 0/1: k-half selector for A/B operands
    const int rsw = l31 & 7;         // read-side swizzle key (row & 7)

    f32x16 acc[2][2] = {};

    for (int kt = 0; kt < KDIM; kt += 64) {
#pragma unroll
        for (int c = 0; c < 4; c++) {
            gl2lds16(gA + (size_t)(c * 8) * KDIM + kt, lA + c * 8 * 64);
            gl2lds16(gB + (size_t)(c * 8) * KDIM + kt, lB + c * 8 * 64);
        }
        __syncthreads();

        // fragment read: for k-step ks (K=16), lane needs 8 bf16 at
        // row = base + l31, k = ks*16 + hi*8 -> global chunk q = ks*2 + hi,
        // stored at LDS chunk q ^ (row&7). 8 consecutive lanes (8 rows)
        // cover all 32 banks exactly once -> conflict-free.
        bf16x8 aF[2][4], bF[2][4];
#pragma unroll
        for (int ks = 0; ks < 4; ks++) {
            const int csw = ((ks * 2 + hi) ^ rsw) * 8;
#pragma unroll
            for (int i = 0; i < 2; i++) {
                aF[i][ks] = *reinterpret_cast<const bf16x8*>(&As[(wrow + i * 32 + l31) * 64 + csw]);
                bF[i][ks] = *reinterpret_cast<const bf16x8*>(&Bs[(wcol + i * 32 + l31) * 64 + csw]);
            }
        }
#pragma unroll
        for (int ks = 0; ks < 4; ks++)
#pragma unroll
            for (int i = 0; i < 2; i++)
#pragma unroll
                for (int j = 0; j < 2; j++)
                    acc[i][j] = __builtin_amdgcn_mfma_f32_32x32x16_bf16(
                        aF[i][ks], bF[j][ks], acc[i][j], 0, 0, 0);
        __syncthreads();
    }

    // epilogue. C/D: col = lane&31, row = (reg&3) + 8*(reg>>2) + 4*(lane>>5)
#pragma unroll
    for (int j = 0; j < 2; j++) {
        const int col = bn + wcol + j * 32 + l31;
        const float bv = bias[col];
#pragma unroll
        for (int i = 0; i < 2; i++) {
            const int rbase = bm + wrow + i * 32 + 4 * hi;
#pragma unroll
            for (int q = 0; q < 4; q++) {
#pragma unroll
                for (int rr = 0; rr < 4; rr++) {
                    const int row = rbase + q * 8 + rr;
                    if (row >= row_lo && row < row_hi) {
                        float v = acc[i][j][q * 4 + rr] + bv;
                        if (!DOWN) {
                            if (e == 0) v = 0.5f * v * (1.0f + erff(v * 0.70710678118654752f));
                            else        v = v > 0.0f ? v : 0.0f;
                            Hb[(size_t)row * NDIM + col] = (__bf16)v;
                        } else {
                            Out[(size_t)perm[row] * HDIM + col] = v;
                        }
                    }
                }
            }
        }
    }
}

extern "C" void kernel_launch(void* const* d_in, const int* in_sizes, int n_in,
                              void* d_out, int out_size, void* d_ws, size_t ws_size,
                              hipStream_t stream) {
    const float* x   = (const float*)d_in[0];
    const float* Wg  = (const float*)d_in[1];
    const float* W0a = (const float*)d_in[2];
    const float* b0a = (const float*)d_in[3];
    const float* W0b = (const float*)d_in[4];
    const float* b0b = (const float*)d_in[5];
    const float* W1a = (const float*)d_in[6];
    const float* b1a = (const float*)d_in[7];
    const float* W1b = (const float*)d_in[8];
    const float* b1b = (const float*)d_in[9];
    float* out = (float*)d_out;

    char* w = (char*)d_ws;
    int* n0   = (int*)(w + CNT_OFF);
    int* n1   = n0 + 1;
    int* perm = (int*)(w + PERM_OFF);
    __bf16* Xg = (__bf16*)(w + XG_OFF);
    __bf16* Wa = (__bf16*)(w + WA_OFF);
    __bf16* Wb = (__bf16*)(w + WB_OFF);
    __bf16* Hb = (__bf16*)(w + HB_OFF);

    (void)hipMemsetAsync(w, 0, 256, stream);
    moe_gate_gather<<<TOKENS / 4, 256, 0, stream>>>(x, Wg, n0, n1, perm, Xg);
    moe_cast_w<<<dim3(4096, 4), 256, 0, stream>>>(W0a, W1a, W0b, W1b, Wa, Wb);
    moe_gemm<HDIM, FDIM, false><<<dim3(FDIM / 128, TOKENS / 128, 2), 256, 0, stream>>>(
        Xg, Wa, b0a, b1a, Hb, nullptr, n0, perm);
    moe_gemm<FDIM, HDIM, true><<<dim3(HDIM / 128, TOKENS / 128, 2), 256, 0, stream>>>(
        Hb, Wb, b0b, b1b, nullptr, out, n0, perm);
}